// Round 4
// baseline (1475.712 us; speedup 1.0000x reference)
//
#include <hip/hip_runtime.h>
#include <hip/hip_bf16.h>

// GPRPropagation: out = sum_k w_k * (D^-1/2 (A+I) D^-1/2)^k x, k=0..ORDER
// N=100000, F=128, E=1600000, ORDER=10.
// dst-sorted CSR build once, then 10 pull-gather rounds (no atomics),
// PPR-weighted accumulation fused into the gather kernel.
// R2: serialized gather (VGPR=4) -> 2.7 TB/s. R3: unroll-4 -> 4.2 TB/s,
// still latency-bound (VALUBusy 10%). R4: unroll-8 to double bytes-in-flight.

#define F 128
#define SCAN_B 256

__global__ void count_kernel(const int* __restrict__ ei, int E,
                             int* __restrict__ cnt) {
    int e = blockIdx.x * blockDim.x + threadIdx.x;
    if (e < E) {
        int c = ei[(size_t)E + e];   // col = destination
        atomicAdd(&cnt[c], 1);
    }
}

__global__ void dinv_kernel(const int* __restrict__ cnt, float* __restrict__ dinv,
                            int N) {
    int i = blockIdx.x * blockDim.x + threadIdx.x;
    if (i < N) {
        dinv[i] = rsqrtf((float)(cnt[i] + 1));  // + self loop
    }
}

__global__ void scan1_kernel(const int* __restrict__ cnt, int* __restrict__ offs,
                             int* __restrict__ bsums, int N) {
    __shared__ int sm[SCAN_B];
    int i = blockIdx.x * SCAN_B + threadIdx.x;
    int v = (i < N) ? cnt[i] : 0;
    sm[threadIdx.x] = v;
    __syncthreads();
    for (int d = 1; d < SCAN_B; d <<= 1) {
        int t = (threadIdx.x >= d) ? sm[threadIdx.x - d] : 0;
        __syncthreads();
        sm[threadIdx.x] += t;
        __syncthreads();
    }
    if (i < N) offs[i] = sm[threadIdx.x] - v;
    if (threadIdx.x == SCAN_B - 1) bsums[blockIdx.x] = sm[SCAN_B - 1];
}

__global__ void scan2_kernel(int* __restrict__ bsums, int nb) {
    __shared__ int sm[SCAN_B];
    __shared__ int carry;
    if (threadIdx.x == 0) carry = 0;
    __syncthreads();
    for (int base = 0; base < nb; base += SCAN_B) {
        int i = base + threadIdx.x;
        int v = (i < nb) ? bsums[i] : 0;
        sm[threadIdx.x] = v;
        __syncthreads();
        for (int d = 1; d < SCAN_B; d <<= 1) {
            int t = (threadIdx.x >= d) ? sm[threadIdx.x - d] : 0;
            __syncthreads();
            sm[threadIdx.x] += t;
            __syncthreads();
        }
        if (i < nb) bsums[i] = sm[threadIdx.x] - v + carry;
        __syncthreads();
        if (threadIdx.x == 0) carry += sm[SCAN_B - 1];
        __syncthreads();
    }
}

__global__ void scan3_kernel(int* __restrict__ offs, const int* __restrict__ bsums,
                             int* __restrict__ cursor, int N, int E) {
    int i = blockIdx.x * blockDim.x + threadIdx.x;
    if (i < N) {
        int o = offs[i] + bsums[i / SCAN_B];
        offs[i] = o;
        cursor[i] = o;
    }
    if (i == N) offs[N] = E;
}

__global__ void place_kernel(const int* __restrict__ ei, int E,
                             const float* __restrict__ dinv,
                             int* __restrict__ cursor, int2* __restrict__ edges) {
    int e = blockIdx.x * blockDim.x + threadIdx.x;
    if (e >= E) return;
    int r = ei[e];
    int c = ei[(size_t)E + e];
    int pos = atomicAdd(&cursor[c], 1);
    float w = dinv[r] * dinv[c];
    int2 p;
    p.x = r;
    p.y = __float_as_int(w);
    edges[pos] = p;
}

// One block per destination node, thread = feature column.
// Manual unroll-8: 8 independent 256B/wave h-row gathers in flight.
__global__ __launch_bounds__(F) void prop_kernel(
    const float* __restrict__ h_old, float* __restrict__ h_new,
    float* __restrict__ out, const float* __restrict__ dinv,
    const int* __restrict__ offs, const int2* __restrict__ edges,
    const float* __restrict__ wts, int k, int first, int last) {
    const int c = blockIdx.x;
    const int f = threadIdx.x;
    const size_t ci = ((size_t)c << 7) + f;

    float hv = h_old[ci];
    float dc = dinv[c];
    float acc = dc * dc * hv;

    int e = offs[c];
    const int end = offs[c + 1];

    for (; e + 8 <= end; e += 8) {
        int2 p0 = edges[e + 0];
        int2 p1 = edges[e + 1];
        int2 p2 = edges[e + 2];
        int2 p3 = edges[e + 3];
        int2 p4 = edges[e + 4];
        int2 p5 = edges[e + 5];
        int2 p6 = edges[e + 6];
        int2 p7 = edges[e + 7];
        float g0 = h_old[((size_t)p0.x << 7) + f];
        float g1 = h_old[((size_t)p1.x << 7) + f];
        float g2 = h_old[((size_t)p2.x << 7) + f];
        float g3 = h_old[((size_t)p3.x << 7) + f];
        float g4 = h_old[((size_t)p4.x << 7) + f];
        float g5 = h_old[((size_t)p5.x << 7) + f];
        float g6 = h_old[((size_t)p6.x << 7) + f];
        float g7 = h_old[((size_t)p7.x << 7) + f];
        acc = fmaf(__int_as_float(p0.y), g0, acc);
        acc = fmaf(__int_as_float(p1.y), g1, acc);
        acc = fmaf(__int_as_float(p2.y), g2, acc);
        acc = fmaf(__int_as_float(p3.y), g3, acc);
        acc = fmaf(__int_as_float(p4.y), g4, acc);
        acc = fmaf(__int_as_float(p5.y), g5, acc);
        acc = fmaf(__int_as_float(p6.y), g6, acc);
        acc = fmaf(__int_as_float(p7.y), g7, acc);
    }
    for (; e < end; ++e) {
        int2 p = edges[e];
        acc = fmaf(__int_as_float(p.y), h_old[((size_t)p.x << 7) + f], acc);
    }

    if (!last) h_new[ci] = acc;
    if (first) {
        out[ci] = wts[0] * hv + wts[1] * acc;
    } else {
        out[ci] = fmaf(wts[k], acc, out[ci]);
    }
}

extern "C" void kernel_launch(void* const* d_in, const int* in_sizes, int n_in,
                              void* d_out, int out_size, void* d_ws, size_t ws_size,
                              hipStream_t stream) {
    const float* x = (const float*)d_in[0];
    const int* ei = (const int*)d_in[1];
    const float* wts = (const float*)d_in[2];
    float* out = (float*)d_out;

    const int NF = in_sizes[0];
    const int N = NF / F;              // 100000
    const int E = in_sizes[1] / 2;     // 1600000
    const int order = in_sizes[2] - 1; // 10

    char* p = (char*)d_ws;
    auto carve = [&](size_t bytes) {
        void* q = (void*)p;
        p += (bytes + 255) & ~(size_t)255;
        return q;
    };
    int nb = (N + SCAN_B - 1) / SCAN_B;
    int*   cnt    = (int*)carve(sizeof(int) * (size_t)N);  // reused as cursor
    int*   offs   = (int*)carve(sizeof(int) * (size_t)(N + 1));
    int*   bsums  = (int*)carve(sizeof(int) * (size_t)nb);
    float* dinv   = (float*)carve(sizeof(float) * (size_t)N);
    int2*  edges  = (int2*)carve(8ull * (size_t)E);
    float* hA     = (float*)carve(sizeof(float) * (size_t)NF);
    float* hB     = (float*)carve(sizeof(float) * (size_t)NF);
    int*   cursor = cnt;  // cnt dead after scan1
    (void)ws_size;

    hipMemsetAsync(cnt, 0, sizeof(int) * (size_t)N, stream);
    count_kernel<<<(E + 255) / 256, 256, 0, stream>>>(ei, E, cnt);
    dinv_kernel<<<(N + 255) / 256, 256, 0, stream>>>(cnt, dinv, N);
    scan1_kernel<<<nb, SCAN_B, 0, stream>>>(cnt, offs, bsums, N);
    scan2_kernel<<<1, SCAN_B, 0, stream>>>(bsums, nb);
    scan3_kernel<<<(N + 1 + 255) / 256, 256, 0, stream>>>(offs, bsums, cursor, N, E);
    place_kernel<<<(E + 255) / 256, 256, 0, stream>>>(ei, E, dinv, cursor, edges);

    const float* hin = x;
    float* hout = hA;
    for (int k = 1; k <= order; ++k) {
        int first = (k == 1);
        int last = (k == order);
        prop_kernel<<<N, F, 0, stream>>>(hin, hout, out, dinv, offs, edges, wts,
                                         k, first, last);
        hin = hout;
        hout = (hout == hA) ? hB : hA;
    }
}

// Round 5
// 927.424 us; speedup vs baseline: 1.5912x; 1.5912x over previous
//
#include <hip/hip_runtime.h>
#include <hip/hip_fp16.h>

// GPRPropagation: out = sum_k w_k * (D^-1/2 (A+I) D^-1/2)^k x, k=0..ORDER
// N=100000, F=128, E=1600000, ORDER=10.
//
// R2: serialized gather -> 2.7 TB/s. R3: unroll-4 -> 4.2 TB/s. R4: unroll-8
// -> identical 132.6us => throughput ceiling (~4.2 TB/s L2-fill), not latency.
// R5: reduce bytes. (a) Horner form y <- P*y + w_j*x kills the out RMW.
// (b) fp16 hidden state halves gather bytes (fp32 accumulate in registers).
// (c) wave-per-node with __half2 lanes: full 512B row = one 256B/wave load.

#define F 128
#define SCAN_B 256

__global__ void count_kernel(const int* __restrict__ ei, int E,
                             int* __restrict__ cnt) {
    int e = blockIdx.x * blockDim.x + threadIdx.x;
    if (e < E) {
        int c = ei[(size_t)E + e];   // col = destination
        atomicAdd(&cnt[c], 1);
    }
}

__global__ void dinv_kernel(const int* __restrict__ cnt, float* __restrict__ dinv,
                            int N) {
    int i = blockIdx.x * blockDim.x + threadIdx.x;
    if (i < N) {
        dinv[i] = rsqrtf((float)(cnt[i] + 1));  // + self loop
    }
}

__global__ void scan1_kernel(const int* __restrict__ cnt, int* __restrict__ offs,
                             int* __restrict__ bsums, int N) {
    __shared__ int sm[SCAN_B];
    int i = blockIdx.x * SCAN_B + threadIdx.x;
    int v = (i < N) ? cnt[i] : 0;
    sm[threadIdx.x] = v;
    __syncthreads();
    for (int d = 1; d < SCAN_B; d <<= 1) {
        int t = (threadIdx.x >= d) ? sm[threadIdx.x - d] : 0;
        __syncthreads();
        sm[threadIdx.x] += t;
        __syncthreads();
    }
    if (i < N) offs[i] = sm[threadIdx.x] - v;
    if (threadIdx.x == SCAN_B - 1) bsums[blockIdx.x] = sm[SCAN_B - 1];
}

__global__ void scan2_kernel(int* __restrict__ bsums, int nb) {
    __shared__ int sm[SCAN_B];
    __shared__ int carry;
    if (threadIdx.x == 0) carry = 0;
    __syncthreads();
    for (int base = 0; base < nb; base += SCAN_B) {
        int i = base + threadIdx.x;
        int v = (i < nb) ? bsums[i] : 0;
        sm[threadIdx.x] = v;
        __syncthreads();
        for (int d = 1; d < SCAN_B; d <<= 1) {
            int t = (threadIdx.x >= d) ? sm[threadIdx.x - d] : 0;
            __syncthreads();
            sm[threadIdx.x] += t;
            __syncthreads();
        }
        if (i < nb) bsums[i] = sm[threadIdx.x] - v + carry;
        __syncthreads();
        if (threadIdx.x == 0) carry += sm[SCAN_B - 1];
        __syncthreads();
    }
}

__global__ void scan3_kernel(int* __restrict__ offs, const int* __restrict__ bsums,
                             int* __restrict__ cursor, int N, int E) {
    int i = blockIdx.x * blockDim.x + threadIdx.x;
    if (i < N) {
        int o = offs[i] + bsums[i / SCAN_B];
        offs[i] = o;
        cursor[i] = o;
    }
    if (i == N) offs[N] = E;
}

__global__ void place_kernel(const int* __restrict__ ei, int E,
                             const float* __restrict__ dinv,
                             int* __restrict__ cursor, int2* __restrict__ edges) {
    int e = blockIdx.x * blockDim.x + threadIdx.x;
    if (e >= E) return;
    int r = ei[e];
    int c = ei[(size_t)E + e];
    int pos = atomicAdd(&cursor[c], 1);
    float w = dinv[r] * dinv[c];
    int2 p;
    p.x = r;
    p.y = __float_as_int(w);
    edges[pos] = p;
}

// x -> fp16 copy, y_init = w[order] * x  (Horner seed)
__global__ void conv_kernel(const float2* __restrict__ x2,
                            __half2* __restrict__ xh, __half2* __restrict__ y,
                            const float* __restrict__ wts, int order, int n2) {
    float wl = wts[order];
    for (int i = blockIdx.x * blockDim.x + threadIdx.x; i < n2;
         i += gridDim.x * blockDim.x) {
        float2 v = x2[i];
        xh[i] = __floats2half2_rn(v.x, v.y);
        y[i] = __floats2half2_rn(wl * v.x, wl * v.y);
    }
}

// One WAVE per destination node; lane = 2 features (__half2).
// y_new[c] = P*y_old[c] + w_j*x[c]; accumulate fp32, store fp16.
// Last round writes fp32 out instead.
__global__ __launch_bounds__(128) void prop_kernel(
    const __half2* __restrict__ y_old, __half2* __restrict__ y_new,
    float2* __restrict__ out, const __half2* __restrict__ xh,
    const float* __restrict__ dinv, const int* __restrict__ offs,
    const int2* __restrict__ edges, const float* __restrict__ wts,
    int j, int last) {
    const int wave = threadIdx.x >> 6;
    const int lane = threadIdx.x & 63;
    const int c = (blockIdx.x << 1) + wave;
    const size_t rb = ((size_t)c << 6);  // row base in half2 units

    const float wj = wts[j];
    const float dc = dinv[c];
    float2 hv = __half22float2(y_old[rb + lane]);
    float2 xv = __half22float2(xh[rb + lane]);
    const float s = dc * dc;
    float accx = fmaf(s, hv.x, wj * xv.x);
    float accy = fmaf(s, hv.y, wj * xv.y);

    int e = offs[c];
    const int end = offs[c + 1];

    for (; e + 8 <= end; e += 8) {
        int2 p0 = edges[e + 0];
        int2 p1 = edges[e + 1];
        int2 p2 = edges[e + 2];
        int2 p3 = edges[e + 3];
        int2 p4 = edges[e + 4];
        int2 p5 = edges[e + 5];
        int2 p6 = edges[e + 6];
        int2 p7 = edges[e + 7];
        float2 f0 = __half22float2(y_old[((size_t)p0.x << 6) + lane]);
        float2 f1 = __half22float2(y_old[((size_t)p1.x << 6) + lane]);
        float2 f2 = __half22float2(y_old[((size_t)p2.x << 6) + lane]);
        float2 f3 = __half22float2(y_old[((size_t)p3.x << 6) + lane]);
        float2 f4 = __half22float2(y_old[((size_t)p4.x << 6) + lane]);
        float2 f5 = __half22float2(y_old[((size_t)p5.x << 6) + lane]);
        float2 f6 = __half22float2(y_old[((size_t)p6.x << 6) + lane]);
        float2 f7 = __half22float2(y_old[((size_t)p7.x << 6) + lane]);
        accx = fmaf(__int_as_float(p0.y), f0.x, accx);
        accy = fmaf(__int_as_float(p0.y), f0.y, accy);
        accx = fmaf(__int_as_float(p1.y), f1.x, accx);
        accy = fmaf(__int_as_float(p1.y), f1.y, accy);
        accx = fmaf(__int_as_float(p2.y), f2.x, accx);
        accy = fmaf(__int_as_float(p2.y), f2.y, accy);
        accx = fmaf(__int_as_float(p3.y), f3.x, accx);
        accy = fmaf(__int_as_float(p3.y), f3.y, accy);
        accx = fmaf(__int_as_float(p4.y), f4.x, accx);
        accy = fmaf(__int_as_float(p4.y), f4.y, accy);
        accx = fmaf(__int_as_float(p5.y), f5.x, accx);
        accy = fmaf(__int_as_float(p5.y), f5.y, accy);
        accx = fmaf(__int_as_float(p6.y), f6.x, accx);
        accy = fmaf(__int_as_float(p6.y), f6.y, accy);
        accx = fmaf(__int_as_float(p7.y), f7.x, accx);
        accy = fmaf(__int_as_float(p7.y), f7.y, accy);
    }
    for (; e < end; ++e) {
        int2 p = edges[e];
        float2 f = __half22float2(y_old[((size_t)p.x << 6) + lane]);
        accx = fmaf(__int_as_float(p.y), f.x, accx);
        accy = fmaf(__int_as_float(p.y), f.y, accy);
    }

    if (last) {
        float2 o;
        o.x = accx;
        o.y = accy;
        out[rb + lane] = o;
    } else {
        y_new[rb + lane] = __floats2half2_rn(accx, accy);
    }
}

extern "C" void kernel_launch(void* const* d_in, const int* in_sizes, int n_in,
                              void* d_out, int out_size, void* d_ws, size_t ws_size,
                              hipStream_t stream) {
    const float* x = (const float*)d_in[0];
    const int* ei = (const int*)d_in[1];
    const float* wts = (const float*)d_in[2];
    float2* out = (float2*)d_out;

    const int NF = in_sizes[0];
    const int N = NF / F;              // 100000
    const int E = in_sizes[1] / 2;     // 1600000
    const int order = in_sizes[2] - 1; // 10

    char* p = (char*)d_ws;
    auto carve = [&](size_t bytes) {
        void* q = (void*)p;
        p += (bytes + 255) & ~(size_t)255;
        return q;
    };
    int nb = (N + SCAN_B - 1) / SCAN_B;
    int*     cnt   = (int*)carve(sizeof(int) * (size_t)N);  // reused as cursor
    int*     offs  = (int*)carve(sizeof(int) * (size_t)(N + 1));
    int*     bsums = (int*)carve(sizeof(int) * (size_t)nb);
    float*   dinv  = (float*)carve(sizeof(float) * (size_t)N);
    int2*    edges = (int2*)carve(8ull * (size_t)E);
    __half2* xh    = (__half2*)carve(sizeof(__half2) * (size_t)(NF / 2));
    __half2* yA    = (__half2*)carve(sizeof(__half2) * (size_t)(NF / 2));
    __half2* yB    = (__half2*)carve(sizeof(__half2) * (size_t)(NF / 2));
    int*     cursor = cnt;  // cnt dead after scan1
    (void)ws_size;

    // ---- CSR build + normalization ----
    hipMemsetAsync(cnt, 0, sizeof(int) * (size_t)N, stream);
    count_kernel<<<(E + 255) / 256, 256, 0, stream>>>(ei, E, cnt);
    dinv_kernel<<<(N + 255) / 256, 256, 0, stream>>>(cnt, dinv, N);
    scan1_kernel<<<nb, SCAN_B, 0, stream>>>(cnt, offs, bsums, N);
    scan2_kernel<<<1, SCAN_B, 0, stream>>>(bsums, nb);
    scan3_kernel<<<(N + 1 + 255) / 256, 256, 0, stream>>>(offs, bsums, cursor, N, E);
    place_kernel<<<(E + 255) / 256, 256, 0, stream>>>(ei, E, dinv, cursor, edges);

    // ---- Horner seed: y = w[order]*x, xh = fp16(x) ----
    conv_kernel<<<2048, 256, 0, stream>>>((const float2*)x, xh, yA, wts, order,
                                          NF / 2);

    // ---- 10 Horner rounds: y <- P*y + w_j*x ; j = order-1 .. 0 ----
    const __half2* yin = yA;
    __half2* yout = yB;
    for (int j = order - 1; j >= 0; --j) {
        int last = (j == 0);
        prop_kernel<<<N / 2, 128, 0, stream>>>(yin, yout, out, xh, dinv, offs,
                                               edges, wts, j, last);
        yin = yout;
        yout = (yout == yA) ? yB : yA;
    }
}

// Round 6
// 913.169 us; speedup vs baseline: 1.6160x; 1.0156x over previous
//
#include <hip/hip_runtime.h>
#include <hip/hip_fp16.h>

// GPRPropagation: out = sum_k w_k * (D^-1/2 (A+I) D^-1/2)^k x, k=0..ORDER
// N=100000, F=128, E=1600000, ORDER=10.
//
// R3/R4: gather throughput wall ~4.2 TB/s (L2-fill). R5: Horner + fp16 hidden
// -> 927us; place_kernel now top dispatch (100us, WRITE 101MB: cross-XCD
// partial-line scatter writeback). R6: (a) dst-range-partitioned place so each
// XCD writes a contiguous CSR slice (full-line writeback, ~7MB); (b) 4B edge
// records (src only), weight dinv[src]*dinv[c] computed in prop via scalar
// loads from L2-resident dinv.

#define F 128
#define SCAN_B 256
#define NGROUP 8

__global__ void count_kernel(const int* __restrict__ ei, int E,
                             int* __restrict__ cnt) {
    int e = blockIdx.x * blockDim.x + threadIdx.x;
    if (e < E) {
        int c = ei[(size_t)E + e];   // col = destination
        atomicAdd(&cnt[c], 1);
    }
}

__global__ void dinv_kernel(const int* __restrict__ cnt, float* __restrict__ dinv,
                            int N) {
    int i = blockIdx.x * blockDim.x + threadIdx.x;
    if (i < N) {
        dinv[i] = rsqrtf((float)(cnt[i] + 1));  // + self loop
    }
}

__global__ void scan1_kernel(const int* __restrict__ cnt, int* __restrict__ offs,
                             int* __restrict__ bsums, int N) {
    __shared__ int sm[SCAN_B];
    int i = blockIdx.x * SCAN_B + threadIdx.x;
    int v = (i < N) ? cnt[i] : 0;
    sm[threadIdx.x] = v;
    __syncthreads();
    for (int d = 1; d < SCAN_B; d <<= 1) {
        int t = (threadIdx.x >= d) ? sm[threadIdx.x - d] : 0;
        __syncthreads();
        sm[threadIdx.x] += t;
        __syncthreads();
    }
    if (i < N) offs[i] = sm[threadIdx.x] - v;
    if (threadIdx.x == SCAN_B - 1) bsums[blockIdx.x] = sm[SCAN_B - 1];
}

__global__ void scan2_kernel(int* __restrict__ bsums, int nb) {
    __shared__ int sm[SCAN_B];
    __shared__ int carry;
    if (threadIdx.x == 0) carry = 0;
    __syncthreads();
    for (int base = 0; base < nb; base += SCAN_B) {
        int i = base + threadIdx.x;
        int v = (i < nb) ? bsums[i] : 0;
        sm[threadIdx.x] = v;
        __syncthreads();
        for (int d = 1; d < SCAN_B; d <<= 1) {
            int t = (threadIdx.x >= d) ? sm[threadIdx.x - d] : 0;
            __syncthreads();
            sm[threadIdx.x] += t;
            __syncthreads();
        }
        if (i < nb) bsums[i] = sm[threadIdx.x] - v + carry;
        __syncthreads();
        if (threadIdx.x == 0) carry += sm[SCAN_B - 1];
        __syncthreads();
    }
}

__global__ void scan3_kernel(int* __restrict__ offs, const int* __restrict__ bsums,
                             int* __restrict__ cursor, int N, int E) {
    int i = blockIdx.x * blockDim.x + threadIdx.x;
    if (i < N) {
        int o = offs[i] + bsums[i / SCAN_B];
        offs[i] = o;
        cursor[i] = o;
    }
    if (i == N) offs[N] = E;
}

// Dst-range-partitioned scatter: group g = blockIdx&7 places only edges whose
// dst is in its N/8 range. CSR slots for that range are contiguous -> writes
// stay in one XCD's L2, lines fully dirtied -> ~7MB writeback vs 101MB.
__global__ void place_kernel(const int* __restrict__ ei, int E,
                             int* __restrict__ cursor, int* __restrict__ edges,
                             int N) {
    const int g = blockIdx.x & (NGROUP - 1);
    const int b = blockIdx.x >> 3;
    const int nb = gridDim.x >> 3;
    const int lo = (int)((long long)N * g / NGROUP);
    const int hi = (int)((long long)N * (g + 1) / NGROUP);
    const int stride = nb * blockDim.x;
    for (int e = b * blockDim.x + threadIdx.x; e < E; e += stride) {
        int c = ei[(size_t)E + e];
        if (c < lo || c >= hi) continue;
        int pos = atomicAdd(&cursor[c], 1);
        edges[pos] = ei[e];
    }
}

// x -> fp16 copy, y_init = w[order] * x  (Horner seed)
__global__ void conv_kernel(const float2* __restrict__ x2,
                            __half2* __restrict__ xh, __half2* __restrict__ y,
                            const float* __restrict__ wts, int order, int n2) {
    float wl = wts[order];
    for (int i = blockIdx.x * blockDim.x + threadIdx.x; i < n2;
         i += gridDim.x * blockDim.x) {
        float2 v = x2[i];
        xh[i] = __floats2half2_rn(v.x, v.y);
        y[i] = __floats2half2_rn(wl * v.x, wl * v.y);
    }
}

// One WAVE per destination node; lane = 2 features (__half2).
// y_new[c] = P*y_old[c] + w_j*x[c]; fp32 accumulate, fp16 store.
// Edge records are src-only (4B); w = dinv[src]*dinv[c] via scalar loads.
__global__ __launch_bounds__(128) void prop_kernel(
    const __half2* __restrict__ y_old, __half2* __restrict__ y_new,
    float2* __restrict__ out, const __half2* __restrict__ xh,
    const float* __restrict__ dinv, const int* __restrict__ offs,
    const int* __restrict__ edges, const float* __restrict__ wts,
    int j, int last) {
    const int wave = threadIdx.x >> 6;
    const int lane = threadIdx.x & 63;
    const int c = (blockIdx.x << 1) + wave;
    const size_t rb = ((size_t)c << 6);  // row base in half2 units

    const float wj = wts[j];
    const float dc = dinv[c];
    float2 hv = __half22float2(y_old[rb + lane]);
    float2 xv = __half22float2(xh[rb + lane]);
    const float s = dc * dc;
    float accx = fmaf(s, hv.x, wj * xv.x);
    float accy = fmaf(s, hv.y, wj * xv.y);

    int e = offs[c];
    const int end = offs[c + 1];

    for (; e + 8 <= end; e += 8) {
        int s0 = edges[e + 0];
        int s1 = edges[e + 1];
        int s2 = edges[e + 2];
        int s3 = edges[e + 3];
        int s4 = edges[e + 4];
        int s5 = edges[e + 5];
        int s6 = edges[e + 6];
        int s7 = edges[e + 7];
        float w0 = dinv[s0] * dc;
        float w1 = dinv[s1] * dc;
        float w2 = dinv[s2] * dc;
        float w3 = dinv[s3] * dc;
        float w4 = dinv[s4] * dc;
        float w5 = dinv[s5] * dc;
        float w6 = dinv[s6] * dc;
        float w7 = dinv[s7] * dc;
        float2 f0 = __half22float2(y_old[((size_t)s0 << 6) + lane]);
        float2 f1 = __half22float2(y_old[((size_t)s1 << 6) + lane]);
        float2 f2 = __half22float2(y_old[((size_t)s2 << 6) + lane]);
        float2 f3 = __half22float2(y_old[((size_t)s3 << 6) + lane]);
        float2 f4 = __half22float2(y_old[((size_t)s4 << 6) + lane]);
        float2 f5 = __half22float2(y_old[((size_t)s5 << 6) + lane]);
        float2 f6 = __half22float2(y_old[((size_t)s6 << 6) + lane]);
        float2 f7 = __half22float2(y_old[((size_t)s7 << 6) + lane]);
        accx = fmaf(w0, f0.x, accx);
        accy = fmaf(w0, f0.y, accy);
        accx = fmaf(w1, f1.x, accx);
        accy = fmaf(w1, f1.y, accy);
        accx = fmaf(w2, f2.x, accx);
        accy = fmaf(w2, f2.y, accy);
        accx = fmaf(w3, f3.x, accx);
        accy = fmaf(w3, f3.y, accy);
        accx = fmaf(w4, f4.x, accx);
        accy = fmaf(w4, f4.y, accy);
        accx = fmaf(w5, f5.x, accx);
        accy = fmaf(w5, f5.y, accy);
        accx = fmaf(w6, f6.x, accx);
        accy = fmaf(w6, f6.y, accy);
        accx = fmaf(w7, f7.x, accx);
        accy = fmaf(w7, f7.y, accy);
    }
    for (; e < end; ++e) {
        int s0 = edges[e];
        float w0 = dinv[s0] * dc;
        float2 f = __half22float2(y_old[((size_t)s0 << 6) + lane]);
        accx = fmaf(w0, f.x, accx);
        accy = fmaf(w0, f.y, accy);
    }

    if (last) {
        float2 o;
        o.x = accx;
        o.y = accy;
        out[rb + lane] = o;
    } else {
        y_new[rb + lane] = __floats2half2_rn(accx, accy);
    }
}

extern "C" void kernel_launch(void* const* d_in, const int* in_sizes, int n_in,
                              void* d_out, int out_size, void* d_ws, size_t ws_size,
                              hipStream_t stream) {
    const float* x = (const float*)d_in[0];
    const int* ei = (const int*)d_in[1];
    const float* wts = (const float*)d_in[2];
    float2* out = (float2*)d_out;

    const int NF = in_sizes[0];
    const int N = NF / F;              // 100000
    const int E = in_sizes[1] / 2;     // 1600000
    const int order = in_sizes[2] - 1; // 10

    char* p = (char*)d_ws;
    auto carve = [&](size_t bytes) {
        void* q = (void*)p;
        p += (bytes + 255) & ~(size_t)255;
        return q;
    };
    int nb = (N + SCAN_B - 1) / SCAN_B;
    int*     cnt   = (int*)carve(sizeof(int) * (size_t)N);  // reused as cursor
    int*     offs  = (int*)carve(sizeof(int) * (size_t)(N + 1));
    int*     bsums = (int*)carve(sizeof(int) * (size_t)nb);
    float*   dinv  = (float*)carve(sizeof(float) * (size_t)N);
    int*     edges = (int*)carve(4ull * (size_t)E);
    __half2* xh    = (__half2*)carve(sizeof(__half2) * (size_t)(NF / 2));
    __half2* yA    = (__half2*)carve(sizeof(__half2) * (size_t)(NF / 2));
    __half2* yB    = (__half2*)carve(sizeof(__half2) * (size_t)(NF / 2));
    int*     cursor = cnt;  // cnt dead after scan1
    (void)ws_size;

    // ---- CSR build + normalization ----
    hipMemsetAsync(cnt, 0, sizeof(int) * (size_t)N, stream);
    count_kernel<<<(E + 255) / 256, 256, 0, stream>>>(ei, E, cnt);
    dinv_kernel<<<(N + 255) / 256, 256, 0, stream>>>(cnt, dinv, N);
    scan1_kernel<<<nb, SCAN_B, 0, stream>>>(cnt, offs, bsums, N);
    scan2_kernel<<<1, SCAN_B, 0, stream>>>(bsums, nb);
    scan3_kernel<<<(N + 1 + 255) / 256, 256, 0, stream>>>(offs, bsums, cursor, N, E);
    place_kernel<<<2048, 256, 0, stream>>>(ei, E, cursor, edges, N);

    // ---- Horner seed: y = w[order]*x, xh = fp16(x) ----
    conv_kernel<<<2048, 256, 0, stream>>>((const float2*)x, xh, yA, wts, order,
                                          NF / 2);

    // ---- 10 Horner rounds: y <- P*y + w_j*x ; j = order-1 .. 0 ----
    const __half2* yin = yA;
    __half2* yout = yB;
    for (int j = order - 1; j >= 0; --j) {
        int last = (j == 0);
        prop_kernel<<<N / 2, 128, 0, stream>>>(yin, yout, out, xh, dinv, offs,
                                               edges, wts, j, last);
        yin = yout;
        yout = (yout == yA) ? yB : yA;
    }
}